// Round 3
// baseline (172.568 us; speedup 1.0000x reference)
//
#include <hip/hip_runtime.h>
#include <hip/hip_cooperative_groups.h>

namespace cg = cooperative_groups;

#define NROWS 512
#define NLAB  16
#define TILE  16
#define GRIDX (NROWS / TILE)      // 32
#define NBLK  (GRIDX * GRIDX)     // 1024

// Single cooperative kernel:
//   phase 1: one block per 16x16 tile of (i,j) row pairs -> 16 label partials to ws
//   grid.sync()
//   phase 2: block (0,0) reduces 1024x16 partials, counts n_pos, writes scalar.
__global__ __launch_bounds__(256) void auc_fused(const int* __restrict__ yt,
                                                 const float* __restrict__ yp,
                                                 float* __restrict__ partial,
                                                 float* __restrict__ out) {
    __shared__ float ya[TILE][TILE];     // yp rows of the i-tile
    __shared__ float yb[TILE][TILE];     // yp rows of the j-tile, pre-biased by +1
    __shared__ unsigned posA[TILE];
    __shared__ unsigned posB[TILE];
    __shared__ float acc[NLAB];

    const int i0 = blockIdx.x * TILE;
    const int j0 = blockIdx.y * TILE;
    const int t = threadIdx.x;

    {
        const int r = t >> 4, c = t & 15;
        ya[r][c] = yp[(i0 + r) * NLAB + c];
        yb[r][c] = yp[(j0 + r) * NLAB + c] + 1.0f;
    }
    if (t < TILE) {
        unsigned pa = 0u, pb = 0u;
        #pragma unroll
        for (int l = 0; l < NLAB; ++l) {
            pa |= (yt[(i0 + t) * NLAB + l] == 1) ? (1u << l) : 0u;
            pb |= (yt[(j0 + t) * NLAB + l] == 1) ? (1u << l) : 0u;
        }
        posA[t] = pa;
        posB[t] = pb;
        acc[t] = 0.0f;
    }
    __syncthreads();

    const int ti = t >> 4;   // i-row within tile
    const int tj = t & 15;   // j-row within tile

    float a[TILE], b[TILE];
    #pragma unroll
    for (int c = 0; c < TILE; ++c) a[c] = ya[ti][c];
    #pragma unroll
    for (int d = 0; d < TILE; ++d) b[d] = yb[tj][d];

    float S = 0.0f;
    #pragma unroll
    for (int d = 0; d < TILE; ++d) {
        #pragma unroll
        for (int c = 0; c < TILE; ++c) {
            S += fmaxf(b[d] - a[c], 0.0f);
        }
    }

    // pos row i AND neg row j per label -> block-local LDS accumulators
    unsigned bits = posA[ti] & ~posB[tj];
    while (bits) {
        const int l = __ffs(bits) - 1;
        bits &= bits - 1;
        atomicAdd(&acc[l], S);
    }
    __syncthreads();

    const int blk = blockIdx.y * gridDim.x + blockIdx.x;
    if (t < NLAB) partial[blk * NLAB + t] = acc[t];
    __threadfence();   // make partials device-visible before the grid barrier

    cg::this_grid().sync();

    if (blockIdx.x != 0 || blockIdx.y != 0) return;

    // ---- phase 2: block (0,0) only ----
    __shared__ float lsum[16][NLAB];
    __shared__ int   lcnt[16][NLAB];
    __shared__ float per_label[NLAB];

    const int lab = t & 15;
    const int grp = t >> 4;   // 0..15

    float s = 0.0f;
    for (int k = 0; k < NBLK / 16; ++k) {
        s += partial[(grp + 16 * k) * NLAB + lab];
    }
    lsum[grp][lab] = s;

    int c = 0;
    for (int k = 0; k < NROWS / 16; ++k) {
        c += (yt[(grp + 16 * k) * NLAB + lab] == 1) ? 1 : 0;
    }
    lcnt[grp][lab] = c;
    __syncthreads();

    if (t < NLAB) {
        float ps = 0.0f;
        int pc = 0;
        #pragma unroll
        for (int g = 0; g < 16; ++g) {
            ps += lsum[g][t];
            pc += lcnt[g][t];
        }
        per_label[t] = ps;
        lcnt[0][t] = pc;
    }
    __syncthreads();

    if (t == 0) {
        double loss = 0.0;
        #pragma unroll
        for (int l = 0; l < NLAB; ++l) {
            const int np_ = lcnt[0][l];
            const int nn_ = NROWS - np_;   // mn = 1 - mp
            if (np_ > 0 && nn_ > 0) {
                const double prod = (double)np_ * (double)nn_;
                const double denom = prod * prod * (double)(NLAB * NLAB);
                loss += (double)per_label[l] / denom;
            }
        }
        out[0] = (float)loss;
    }
}

extern "C" void kernel_launch(void* const* d_in, const int* in_sizes, int n_in,
                              void* d_out, int out_size, void* d_ws, size_t ws_size,
                              hipStream_t stream) {
    const int* y_true = (const int*)d_in[0];
    const float* y_pred = (const float*)d_in[1];
    float* out = (float*)d_out;
    float* partial = (float*)d_ws;   // NBLK*NLAB floats = 64 KB

    dim3 grid(GRIDX, GRIDX);   // 32 x 32 = 1024 blocks, 4 waves each -> co-resident
    dim3 block(256);
    void* args[] = {(void*)&y_true, (void*)&y_pred, (void*)&partial, (void*)&out};
    hipLaunchCooperativeKernel((const void*)auc_fused, grid, block, args, 0, stream);
}

// Round 4
// 131.750 us; speedup vs baseline: 1.3098x; 1.3098x over previous
//
#include <hip/hip_runtime.h>

#define NROWS 512
#define NLAB  16
#define TILE  16
#define GRIDX (NROWS / TILE)      // 32
#define NBLK  (GRIDX * GRIDX)     // 1024
#define MAGIC 0x5EEDF00Du

// Single kernel, no grid barrier:
//  - every block computes its 16x16 (i,j) tile's 16 label partials -> ws,
//    then release-stores a MAGIC flag (agent scope).
//  - block 0 additionally acquire-spins on all 1024 flags (producers never
//    wait), then reduces partials, counts n_pos, writes the scalar loss,
//    and resets flags to 0 so no launch depends on prior ws state.
__global__ __launch_bounds__(256) void auc_all(const int* __restrict__ yt,
                                               const float* __restrict__ yp,
                                               float* __restrict__ partial,
                                               unsigned* __restrict__ flags,
                                               float* __restrict__ out) {
    __shared__ float ya[TILE][TILE];       // yp rows of the i-tile
    __shared__ float yb[TILE][TILE];       // yp rows of the j-tile, pre-biased +1
    __shared__ float S_tile[TILE][TILE + 1];
    __shared__ unsigned posA[TILE];
    __shared__ unsigned posB[TILE];
    __shared__ float lsum[16][NLAB];
    __shared__ int   lcnt[16][NLAB];
    __shared__ float pl_s[NLAB];
    __shared__ int   pl_c[NLAB];

    const int i0 = blockIdx.x * TILE;
    const int j0 = blockIdx.y * TILE;
    const int t  = threadIdx.x;
    const int r  = t >> 4;     // 0..15
    const int c  = t & 15;     // 0..15

    // Stage yp rows (coalesced) and build per-row pos bitmasks via ballot.
    ya[r][c] = yp[(i0 + r) * NLAB + c];
    yb[r][c] = yp[(j0 + r) * NLAB + c] + 1.0f;
    {
        // lane = (r&3)*16 + c within each wave; ballot packs 4 rows x 16 labels.
        unsigned long long ba = __ballot(yt[(i0 + r) * NLAB + c] == 1);
        unsigned long long bb = __ballot(yt[(j0 + r) * NLAB + c] == 1);
        if (c == 0) {
            posA[r] = (unsigned)((ba >> ((r & 3) * 16)) & 0xFFFFull);
            posB[r] = (unsigned)((bb >> ((r & 3) * 16)) & 0xFFFFull);
        }
    }
    __syncthreads();

    // S[r][c] = sum_{cc,d} relu(1 - yp[i0+r][cc] + yp[j0+c][d])
    float a[TILE], b[TILE];
    #pragma unroll
    for (int k = 0; k < TILE; ++k) a[k] = ya[r][k];
    #pragma unroll
    for (int k = 0; k < TILE; ++k) b[k] = yb[c][k];

    float S = 0.0f;
    #pragma unroll
    for (int d = 0; d < TILE; ++d) {
        #pragma unroll
        for (int cc = 0; cc < TILE; ++cc) {
            S += fmaxf(b[d] - a[cc], 0.0f);
        }
    }
    S_tile[r][c] = S;
    __syncthreads();

    // Bilinear form per label: thread (l=r, ti=c) does the masked row-sum,
    // gates by posA, then 4-step shfl_xor reduce over ti (low 4 lane bits).
    {
        const int l = r, ti = c;
        float rowsum = 0.0f;
        #pragma unroll
        for (int tj = 0; tj < TILE; ++tj) {
            if (((~posB[tj]) >> l) & 1u) rowsum += S_tile[ti][tj];
        }
        float val = ((posA[ti] >> l) & 1u) ? rowsum : 0.0f;
        val += __shfl_xor(val, 1);
        val += __shfl_xor(val, 2);
        val += __shfl_xor(val, 4);
        val += __shfl_xor(val, 8);
        const int blk = blockIdx.y * GRIDX + blockIdx.x;
        if (ti == 0) partial[blk * NLAB + l] = val;
    }

    __threadfence();
    __syncthreads();
    const int blk = blockIdx.y * GRIDX + blockIdx.x;
    if (t == 0) {
        __hip_atomic_store(&flags[blk], MAGIC, __ATOMIC_RELEASE, __HIP_MEMORY_SCOPE_AGENT);
    }
    if (blk != 0) return;

    // ---- finalizer: block 0 only ----
    for (int i = t; i < NBLK; i += 256) {
        while (__hip_atomic_load(&flags[i], __ATOMIC_ACQUIRE, __HIP_MEMORY_SCOPE_AGENT) != MAGIC) {}
    }
    __syncthreads();

    // Reset flags so no future launch can see stale MAGIC.
    for (int i = t; i < NBLK; i += 256) {
        __hip_atomic_store(&flags[i], 0u, __ATOMIC_RELAXED, __HIP_MEMORY_SCOPE_AGENT);
    }

    const int lab = t & 15;
    const int grp = t >> 4;   // 0..15

    float s = 0.0f;
    for (int k = 0; k < NBLK / 16; ++k) {
        s += partial[(grp + 16 * k) * NLAB + lab];   // coalesced per iteration
    }
    lsum[grp][lab] = s;

    int cnt = 0;
    for (int k = 0; k < NROWS / 16; ++k) {
        cnt += (yt[(grp + 16 * k) * NLAB + lab] == 1) ? 1 : 0;
    }
    lcnt[grp][lab] = cnt;
    __syncthreads();

    if (t < NLAB) {
        float ps = 0.0f;
        int pc = 0;
        #pragma unroll
        for (int g = 0; g < 16; ++g) {
            ps += lsum[g][t];
            pc += lcnt[g][t];
        }
        pl_s[t] = ps;
        pl_c[t] = pc;
    }
    __syncthreads();

    if (t == 0) {
        double loss = 0.0;
        #pragma unroll
        for (int l = 0; l < NLAB; ++l) {
            const int np_ = pl_c[l];
            const int nn_ = NROWS - np_;   // mn = 1 - mp
            if (np_ > 0 && nn_ > 0) {
                const double prod = (double)np_ * (double)nn_;
                const double denom = prod * prod * (double)(NLAB * NLAB);
                loss += (double)pl_s[l] / denom;
            }
        }
        out[0] = (float)loss;
    }
}

extern "C" void kernel_launch(void* const* d_in, const int* in_sizes, int n_in,
                              void* d_out, int out_size, void* d_ws, size_t ws_size,
                              hipStream_t stream) {
    const int* y_true = (const int*)d_in[0];
    const float* y_pred = (const float*)d_in[1];
    float* out = (float*)d_out;
    float* partial = (float*)d_ws;                     // NBLK*NLAB floats (64 KB)
    unsigned* flags = (unsigned*)(partial + NBLK * NLAB);  // NBLK u32 (4 KB)

    dim3 grid(GRIDX, GRIDX);   // 1024 blocks
    auc_all<<<grid, 256, 0, stream>>>(y_true, y_pred, partial, flags, out);
}